// Round 10
// baseline (40.976 us; speedup 1.0000x reference)
//
#include <hip/hip_runtime.h>
#include <hip/hip_bf16.h>

typedef __attribute__((ext_vector_type(8))) short bf16x8;   // 8 bf16 (4 VGPRs)
typedef __attribute__((ext_vector_type(4))) float f32x4;    // MFMA accumulator

#define CA_EPS 1e-6f

__device__ __forceinline__ unsigned short f2bf(float f) {
  // round-to-nearest-even bf16
  unsigned u = __float_as_uint(f);
  u += 0x7fffu + ((u >> 16) & 1u);
  return (unsigned short)(u >> 16);
}

// Gate + L2-normalize each 128-float row, emit bf16. One launch covers both
// X (blocks [0, rowsX/8)) and Y (blocks above).
__global__ void __launch_bounds__(256) gate_norm_kernel(
    const float* __restrict__ X, const float* __restrict__ A1,
    const float* __restrict__ Y, const float* __restrict__ A2,
    unsigned short* __restrict__ outX, unsigned short* __restrict__ outY,
    int rowsX) {
  int row = (int)((blockIdx.x * 256 + threadIdx.x) >> 5);
  int l = threadIdx.x & 31;
  const float* src;
  const float* gate;
  unsigned short* dst;
  if (row < rowsX) {
    src = X; gate = A1; dst = outX;
  } else {
    src = Y; gate = A2; dst = outY; row -= rowsX;
  }
  const float4 x = *(const float4*)(src + (size_t)row * 128 + l * 4);
  const float4 a = *(const float4*)(gate + (size_t)row * 128 + l * 4);
  float g0 = x.x * a.x, g1 = x.y * a.y, g2 = x.z * a.z, g3 = x.w * a.w;
  float ss = g0 * g0 + g1 * g1 + g2 * g2 + g3 * g3;
#pragma unroll
  for (int off = 16; off; off >>= 1) ss += __shfl_xor(ss, off);
  float inv = 1.0f / sqrtf(fmaxf(ss, CA_EPS));
  ushort4 o;
  o.x = f2bf(g0 * inv);
  o.y = f2bf(g1 * inv);
  o.z = f2bf(g2 * inv);
  o.w = f2bf(g3 * inv);
  *(ushort4*)(dst + (size_t)row * 128 + l * 4) = o;
}

#define GLOAD_LDS16(g, l)                                        \
  __builtin_amdgcn_global_load_lds(                              \
      (const __attribute__((address_space(1))) void*)(g),        \
      (__attribute__((address_space(3))) void*)(l), 16, 0, 0)

// R7 structure (proven best: XCD = batch = id&7, 64x256 tile, 8 waves,
// swizzled global_load_lds staging) with ONE change: the epilogue routes acc
// through an LDS transpose so every wave store instruction writes a fully
// contiguous 1 KB run (8 complete 128B cache lines) -- instruction-identical
// to fillBuffer's 7 TB/s store pattern. Tests the partial-line-RFO theory.
// LDS: 80 KB char pool; staging view (A 16 KB + B 64 KB) is dead after the
// compute loop and is reused as the 64x264-f32 transpose buffer (67.6 KB).
__global__ void __launch_bounds__(512, 4) cosine_gemm_kernel(
    const unsigned short* __restrict__ Xn,  // (B, 2048, 128) bf16
    const unsigned short* __restrict__ Yn,  // (B, 2048, 128) bf16
    float* __restrict__ C) {                // (B, 2048, 2048) f32
  __shared__ __align__(16) char smem[81920];  // 80 KB -> 2 blocks/CU
  unsigned short* ldsA = (unsigned short*)smem;            // 16 KB
  unsigned short* ldsB = (unsigned short*)(smem + 16384);  // 64 KB
  float* ldsT = (float*)smem;                              // 64 x 264 f32

  const int tid = threadIdx.x;
  const int lane = tid & 63;
  const int w = tid >> 6;  // wave 0..7 = column slab (32 cols each)

  // XCD-major decomposition: XCD = batch, panels within batch stay local.
  const int id = blockIdx.x;
  const int b = id & 7;        // batch == XCD (round-robin dispatch)
  const int p = id >> 3;       // 256 panel tiles per batch
  const int tn = p & 31;       // 64-row slab of X / C rows (32 tiles)
  const int tm = p >> 5;       // 256-col slab of Y / C cols (8 tiles)

  const unsigned short* Asrc = Xn + ((size_t)b * 2048 + (size_t)tn * 64) * 128;
  const unsigned short* Bsrc = Yn + ((size_t)b * 2048 + (size_t)tm * 256) * 128;

  // Stage A: 1024 16B-chunks (2/thread); B: 4096 chunks (8/thread).
  // LDS dest linear; global source chunk inverse-swizzled (rule #21) so LDS
  // chunk p holds global chunk p ^ (row&7) -> conflict-free fragment reads.
#pragma unroll
  for (int i = 0; i < 2; ++i) {
    int pp = i * 512 + tid;
    int q = (pp & ~15) | ((pp & 15) ^ ((pp >> 4) & 7));
    GLOAD_LDS16(Asrc + (size_t)q * 8, &ldsA[(i * 512 + w * 64) * 8]);
  }
#pragma unroll
  for (int i = 0; i < 8; ++i) {
    int pp = i * 512 + tid;
    int q = (pp & ~15) | ((pp & 15) ^ ((pp >> 4) & 7));
    GLOAD_LDS16(Bsrc + (size_t)q * 8, &ldsB[(i * 512 + w * 64) * 8]);
  }
  __syncthreads();

  f32x4 acc[4][2] = {};
  const int r16 = lane & 15;  // frag row (A) / frag col (B,C)
  const int kq = lane >> 4;   // k-quarter 0..3

#pragma unroll
  for (int kk = 0; kk < 4; ++kk) {
    const int kc = kk * 4 + kq;  // 8-element K-chunk index (0..15)
    bf16x8 af[4], bfr[2];
#pragma unroll
    for (int mi = 0; mi < 4; ++mi) {
      int r = mi * 16 + r16;  // A row 0..63
      af[mi] = *(const bf16x8*)(&ldsA[r * 128 + ((kc ^ (r & 7)) * 8)]);
    }
#pragma unroll
    for (int ni = 0; ni < 2; ++ni) {
      int r = w * 32 + ni * 16 + r16;  // B row 0..255
      bfr[ni] = *(const bf16x8*)(&ldsB[r * 128 + ((kc ^ (r & 7)) * 8)]);
    }
#pragma unroll
    for (int mi = 0; mi < 4; ++mi)
#pragma unroll
      for (int ni = 0; ni < 2; ++ni)
        acc[mi][ni] = __builtin_amdgcn_mfma_f32_16x16x32_bf16(
            af[mi], bfr[ni], acc[mi][ni], 0, 0, 0);
  }

  // ---- Epilogue via LDS transpose ----
  // Phase A: scatter acc into ldsT[row][col], stride 264 f32 (264%32==8 ->
  // the 4 kq-rows of one write instruction land on disjoint bank octets:
  // 2-way conflict = free). MFMA C/D layout: col = lane&15 (C col here is
  // w*32 + ni*16 + r16), row = kq*4 + reg j within mi*16.
  __syncthreads();  // all waves done reading ldsA/ldsB
#pragma unroll
  for (int mi = 0; mi < 4; ++mi)
#pragma unroll
    for (int ni = 0; ni < 2; ++ni)
#pragma unroll
      for (int j = 0; j < 4; ++j)
        ldsT[(mi * 16 + kq * 4 + j) * 264 + w * 32 + ni * 16 + r16] =
            acc[mi][ni][j];
  __syncthreads();

  // Phase B: wave w stores rows [w*8, w*8+8); per instruction the 64 lanes
  // cover one FULL 1 KB C-row run (lane*16 B contiguous = 8 whole 128 B
  // lines) -- the fillBuffer store pattern.
  float* Crow = C + ((size_t)b * 2048 + (size_t)tn * 64) * 2048 +
                (size_t)tm * 256;
#pragma unroll
  for (int it = 0; it < 8; ++it) {
    int r = w * 8 + it;
    f32x4 v = *(const f32x4*)(&ldsT[r * 264 + lane * 4]);
    *(f32x4*)(Crow + (size_t)r * 2048 + lane * 4) = v;
  }
}

extern "C" void kernel_launch(void* const* d_in, const int* in_sizes, int n_in,
                              void* d_out, int out_size, void* d_ws, size_t ws_size,
                              hipStream_t stream) {
  const float* X  = (const float*)d_in[0];
  const float* Y  = (const float*)d_in[1];
  const float* A1 = (const float*)d_in[2];
  const float* A2 = (const float*)d_in[3];
  float* C = (float*)d_out;

  const int B = 8, N = 2048, M = 2048, D = 128;

  unsigned short* Xn = (unsigned short*)d_ws;    // (B,N,128) bf16
  unsigned short* Yn = Xn + (size_t)B * N * D;   // (B,M,128) bf16

  const int rowsX = B * N, rowsY = B * M;
  gate_norm_kernel<<<dim3((rowsX + rowsY) / 8), dim3(256), 0, stream>>>(
      X, A1, Y, A2, Xn, Yn, rowsX);
  // 1D grid: 2048 blocks, XCD = id & 7 = batch.
  cosine_gemm_kernel<<<dim3((N / 64) * (M / 256) * B), dim3(512), 0, stream>>>(
      Xn, Yn, C);
}